// Round 7
// baseline (185.754 us; speedup 1.0000x reference)
//
#include <hip/hip_runtime.h>
#include <math.h>

// Problem constants (from reference)
#define NB      2048        // batch
#define DIM     256         // input dim
#define SC6     192         // S*6 = 32 splines * 6 params
#define CV      128         // canvas size
#define NT      50          // samples along curve
#define BPB     8           // batches per gemm block (W amortization)
// W_STAMP = -0.07, BG = 0.3, SCALE = 1e-4

// log_prob per batch = 192*( -ln(1e-4) - 0.5*ln(2*pi) )  (raw == mu exactly)
// entropy  per batch = 192*( 0.5 + 0.5*ln(2*pi) + ln(1e-4) )
#define LPV  (1591.9491530441301f)
#define ENV  (-1495.9491530441301f)

// Output layout (flat, return order): sketch | log_prob | entropy | sample
#define SKETCH_N   ((size_t)NB * CV * CV)     // 33,554,432
#define LP_OFF     (SKETCH_N)
#define ENT_OFF    (LP_OFF + NB)
#define SAMPLE_OFF (ENT_OFF + NB)

// native vector type (HIP float4 is a class -> rejected by nontemporal builtin)
typedef float vfloat4 __attribute__((ext_vector_type(4)));

// ---------------------------------------------------------------------------
// Kernel 1: blocked GEMM + sigmoid. 256 blocks x 192 thr, 8 batches/block.
// W[d][j] is loaded ONCE per 8 batches (W L2 traffic 200->50 MB; the R6 win
// showed the fused gemm was W-L2-bound). Per-(b,j) the d-loop remains a
// single sequential f64 fma chain d=0..255 -> mu bit-identical to all prior
// passing rounds. Emits sample (f32), lp/ent constants, params*128 (f64->ws).
// ---------------------------------------------------------------------------
__global__ __launch_bounds__(192) void gemm_kernel(
    const float* __restrict__ x, const float* __restrict__ W,
    const float* __restrict__ bias, float* __restrict__ out,
    double* __restrict__ params)
{
    __shared__ float xs[BPB][DIM];               // 8 KB x-tile
    const int b0  = blockIdx.x * BPB;
    const int tid = threadIdx.x;                 // 0..191

    for (int i = tid; i < BPB * DIM; i += 192) { // coalesced x stage
        int bl = i >> 8;
        int d  = i & 255;
        xs[bl][d] = x[(size_t)(b0 + bl) * DIM + d];
    }
    __syncthreads();

    const int j = tid;
    double acc[BPB] = {0, 0, 0, 0, 0, 0, 0, 0};

    #pragma unroll 4
    for (int d = 0; d < DIM; ++d) {
        double wd = (double)W[d * SC6 + j];      // one load, 8 FMAs
        #pragma unroll
        for (int bl = 0; bl < BPB; ++bl)
            acc[bl] = fma((double)xs[bl][d], wd, acc[bl]);
    }

    const double bj = (double)bias[j];
    #pragma unroll
    for (int bl = 0; bl < BPB; ++bl) {
        double s = 1.0 / (1.0 + exp(-(acc[bl] + bj)));
        out[SAMPLE_OFF + (size_t)(b0 + bl) * SC6 + j] = (float)s;
        params[(size_t)(b0 + bl) * SC6 + j] = s * 128.0;   // CANVAS scale
    }

    if (tid < BPB)           out[LP_OFF  + b0 + tid]       = LPV;
    else if (tid < 2 * BPB)  out[ENT_OFF + b0 + tid - BPB] = ENV;
}

// ---------------------------------------------------------------------------
// Kernel 2: paint. 2048 blocks x 256 thr (8 blocks/CU, 100% occupancy).
// Front phase is tiny (params 1.5 KB + 16 KB zero + coeff table) so the
// store-dominated epilogue starts almost immediately -> near write-BW.
// u8-packed canvas (4 px/u32, 16 KB; max stamps/px way <255, self-detecting),
// y-triple packs into 1-2 words (~4.5 atomics/point), per-row bank rotation.
// ---------------------------------------------------------------------------
__global__ __launch_bounds__(256) void paint_kernel(
    const double* __restrict__ params, float* __restrict__ out)
{
    __shared__ unsigned int cnt[CV * CV / 4];     // 4096 words, 16 KB
    __shared__ double sp[6][32];                  // SoA params*128
    __shared__ double cfa[NT], cfb[NT], cfc[NT];  // (1-t)^2, 2(1-t)t, t^2

    const int b   = blockIdx.x;
    const int tid = threadIdx.x;

    {   // zero canvas: 1024 uint4 / 256 thr = 4 each
        uint4* c4 = (uint4*)cnt;
        uint4 z = make_uint4(0u, 0u, 0u, 0u);
        #pragma unroll
        for (int w = 0; w < 4; ++w) c4[tid + 256 * w] = z;
    }
    if (tid < SC6) {
        double v = params[(size_t)b * SC6 + tid];
        sp[tid % 6][tid / 6] = v;
    } else {
        int t2 = tid - SC6;                       // 0..63
        if (t2 < NT) {
            // np.linspace(0,1,50): t_k = k*fl64(1/49), endpoint forced to 1.0
            double t = (t2 == NT - 1) ? 1.0 : (double)t2 * (1.0 / 49.0);
            double u = 1.0 - t;
            cfa[t2] = u * u;                      // (1-t)**2
            cfb[t2] = (2.0 * u) * t;              // 2*(1-t)*t (ref assoc order)
            cfc[t2] = t * t;                      // t**2
        }
    }
    __syncthreads();

    // ---- paint: lane map s=i%32 scatters lanes across splines ----
    for (int i = tid; i < 32 * NT; i += 256) {
        int s = i & 31;
        int k = i >> 5;                           // 0..49
        double a  = cfa[k];
        double bq = cfb[k];
        double c  = cfc[k];
        double px = a * sp[0][s] + bq * sp[2][s] + c * sp[4][s];
        double py = a * sp[1][s] + bq * sp[3][s] + c * sp[5][s];
        int cx = (int)rint(px);                   // round-half-even == np.round
        int cy = (int)rint(py);

        // clipped y-triple -> u8 increments for 1-2 adjacent 4-px words
        int y0 = min(max(cy - 1, 0), CV - 1);
        int y1 = min(max(cy,     0), CV - 1);
        int y2 = min(max(cy + 1, 0), CV - 1);
        int cb = y0 >> 2;                         // base word-column (0..31)
        unsigned incA = 1u << ((y0 & 3) << 3);
        unsigned incB = 0u;
        unsigned i1 = 1u << ((y1 & 3) << 3);
        unsigned i2 = 1u << ((y2 & 3) << 3);
        if ((y1 >> 2) == cb) incA += i1; else incB += i1;
        if ((y2 >> 2) == cb) incA += i2; else incB += i2;

        int x0 = min(max(cx - 1, 0), CV - 1);
        int x1 = min(max(cx,     0), CV - 1);
        int x2 = min(max(cx + 1, 0), CV - 1);
        int rows[3] = {x0, x1, x2};
        #pragma unroll
        for (int r = 0; r < 3; ++r) {
            int xi = rows[r];
            int base = xi << 5;
            atomicAdd(&cnt[base + ((cb + xi) & 31)], incA);
            if (incB) atomicAdd(&cnt[base + ((cb + 1 + xi) & 31)], incB);
        }
    }
    __syncthreads();

    // ---- epilogue: word w <-> output float4 w, nontemporal stores ----
    vfloat4* ob = (vfloat4*)(out + (size_t)b * CV * CV);
    for (int w = tid; w < CV * CV / 4; w += 256) {
        int xi  = w >> 5;                         // row
        int idx = (xi << 5) + (((w & 31) + xi) & 31);
        unsigned v = cnt[idx];
        vfloat4 r;
        r.x = fminf(fmaxf(0.3f - 0.07f * (float)( v        & 255u), 0.0f), 1.0f);
        r.y = fminf(fmaxf(0.3f - 0.07f * (float)((v >>  8) & 255u), 0.0f), 1.0f);
        r.z = fminf(fmaxf(0.3f - 0.07f * (float)((v >> 16) & 255u), 0.0f), 1.0f);
        r.w = fminf(fmaxf(0.3f - 0.07f * (float)( v >> 24        ), 0.0f), 1.0f);
        __builtin_nontemporal_store(r, &ob[w]);
    }
}

extern "C" void kernel_launch(void* const* d_in, const int* in_sizes, int n_in,
                              void* d_out, int out_size, void* d_ws, size_t ws_size,
                              hipStream_t stream) {
    const float* x    = (const float*)d_in[0];   // [2048, 256]
    const float* W    = (const float*)d_in[1];   // [256, 192]
    const float* bias = (const float*)d_in[2];   // [192]
    float* out = (float*)d_out;
    double* params = (double*)d_ws;              // [2048,192] f64 = 3.1 MB

    gemm_kernel<<<NB / BPB, 192, 0, stream>>>(x, W, bias, out, params);
    paint_kernel<<<NB, 256, 0, stream>>>(params, out);
}

// Round 8
// 162.572 us; speedup vs baseline: 1.1426x; 1.1426x over previous
//
#include <hip/hip_runtime.h>
#include <math.h>

// Problem constants (from reference)
#define NB      2048        // batch
#define DIM     256         // input dim
#define SC6     192         // S*6 = 32 splines * 6 params
#define CV      128         // canvas size
#define NT      50          // samples along curve
#define NBPB    2           // batches per block (W amortization)
// W_STAMP = -0.07, BG = 0.3, SCALE = 1e-4

// log_prob per batch = 192*( -ln(1e-4) - 0.5*ln(2*pi) )  (raw == mu exactly)
// entropy  per batch = 192*( 0.5 + 0.5*ln(2*pi) + ln(1e-4) )
#define LPV  (1591.9491530441301f)
#define ENV  (-1495.9491530441301f)

// Output layout (flat, return order): sketch | log_prob | entropy | sample
#define SKETCH_N   ((size_t)NB * CV * CV)     // 33,554,432
#define LP_OFF     (SKETCH_N)
#define ENT_OFF    (LP_OFF + NB)
#define SAMPLE_OFF (ENT_OFF + NB)

// native vector type (HIP float4 is a class -> rejected by nontemporal builtin)
typedef float vfloat4 __attribute__((ext_vector_type(4)));

// Workgroup barrier that waits ONLY on LDS ops (lgkmcnt), NOT on outstanding
// global stores. __syncthreads() would emit s_waitcnt vmcnt(0) before
// s_barrier, draining the epilogue's 64 KB of nontemporal stores on the
// critical path (the m97 barrier-drain stall). Inter-phase correctness here
// only ever needs LDS visibility.
__device__ __forceinline__ void barrier_lds_only() {
    asm volatile("s_waitcnt lgkmcnt(0)\n\ts_barrier" ::: "memory");
}

// ---------------------------------------------------------------------------
// Fused kernel (R6 structure + store-drain-free barriers), one block (512
// thr) per TWO batches; grid 1024 = 4 blocks/CU, 32 waves/CU.
//  waves 0-2 (tid<192): thread j computes mu for BOTH batches reading W[d][j]
//      once (halves W L2 traffic; the R6 win); f64 sequential d=0..255 chain
//      per batch bit-identical to all passing rounds; sigmoid f64; sample ->
//      global; params*128 -> LDS SoA.
//  waves 3-7, CONCURRENT: zero canvas, 50-entry f64 Bezier coeff table
//      (identical op sequence), lp/ent constants.
//  per batch: paint u8-packed canvas (4 px/u32, 16 KB), y-triple in 1-2
//      words (~4.5 atomics/point), per-row bank rotation; epilogue
//      clip(0.3-0.07*cnt,0,1) f32 nontemporal float4 stores + re-zero.
//  All interior barriers are lgkmcnt-only: batch-0 stores drain under
//      batch-1 compute; nothing drains before s_endpgm.
// ---------------------------------------------------------------------------
__global__ __launch_bounds__(512) void fused_kernel(
    const float* __restrict__ x, const float* __restrict__ W,
    const float* __restrict__ bias, float* __restrict__ out)
{
    __shared__ unsigned int cnt[CV * CV / 4];     // 4096 words, u8-packed, 16 KB
    __shared__ double sp[NBPB][6][32];            // SoA params*128, both batches
    __shared__ double cfa[NT], cfb[NT], cfc[NT];  // (1-t)^2, 2(1-t)t, t^2

    const int b0  = blockIdx.x * NBPB;
    const int tid = threadIdx.x;

    if (tid < SC6) {
        // ---- gemm + sigmoid, 2 batches, W loaded once (f64 exact chain) ----
        const int j = tid;
        const float* xb0 = x + (size_t)b0 * DIM;  // wave-uniform -> s_load
        const float* xb1 = xb0 + DIM;
        double a0 = 0.0, a1 = 0.0;
        #pragma unroll 8
        for (int d = 0; d < DIM; ++d) {
            double wd = (double)W[d * SC6 + j];
            a0 = fma((double)xb0[d], wd, a0);
            a1 = fma((double)xb1[d], wd, a1);
        }
        double bj = (double)bias[j];
        double s0 = 1.0 / (1.0 + exp(-(a0 + bj)));
        double s1 = 1.0 / (1.0 + exp(-(a1 + bj)));
        out[SAMPLE_OFF + (size_t)b0 * SC6 + j]       = (float)s0;
        out[SAMPLE_OFF + (size_t)(b0 + 1) * SC6 + j] = (float)s1;
        sp[0][j % 6][j / 6] = s0 * 128.0;         // CANVAS scale, SoA
        sp[1][j % 6][j / 6] = s1 * 128.0;
    } else {
        // ---- waves 3-7: canvas zero + coeff table + consts (concurrent) ----
        const int t2 = tid - SC6;                 // 0..319
        uint4* c4 = (uint4*)cnt;                  // 1024 uint4 words
        uint4 z = make_uint4(0u, 0u, 0u, 0u);
        for (int w = t2; w < 1024; w += 320) c4[w] = z;
        if (t2 < NT) {
            // np.linspace(0,1,50): t_k = k*fl64(1/49), endpoint forced to 1.0
            double t = (t2 == NT - 1) ? 1.0 : (double)t2 * (1.0 / 49.0);
            double u = 1.0 - t;
            cfa[t2] = u * u;                      // (1-t)**2
            cfb[t2] = (2.0 * u) * t;              // 2*(1-t)*t (ref assoc order)
            cfc[t2] = t * t;                      // t**2
        }
        if (t2 == 60) out[LP_OFF  + b0]     = LPV;
        if (t2 == 61) out[ENT_OFF + b0]     = ENV;
        if (t2 == 62) out[LP_OFF  + b0 + 1] = LPV;
        if (t2 == 63) out[ENT_OFF + b0 + 1] = ENV;
    }
    barrier_lds_only();

    #pragma unroll
    for (int bb = 0; bb < NBPB; ++bb) {
        // ---- paint: lane map s=i%32 scatters lanes across splines ----
        for (int i = tid; i < 32 * NT; i += 512) {
            int s = i & 31;
            int k = i >> 5;                       // 0..49
            double a  = cfa[k];
            double bq = cfb[k];
            double c  = cfc[k];
            double px = a * sp[bb][0][s] + bq * sp[bb][2][s] + c * sp[bb][4][s];
            double py = a * sp[bb][1][s] + bq * sp[bb][3][s] + c * sp[bb][5][s];
            int cx = (int)rint(px);               // round-half-even == np.round
            int cy = (int)rint(py);

            // clipped y-triple -> u8 increments for 1-2 adjacent 4-px words
            int y0 = min(max(cy - 1, 0), CV - 1);
            int y1 = min(max(cy,     0), CV - 1);
            int y2 = min(max(cy + 1, 0), CV - 1);
            int cb = y0 >> 2;                     // base word-column (0..31)
            unsigned incA = 1u << ((y0 & 3) << 3);
            unsigned incB = 0u;
            unsigned i1 = 1u << ((y1 & 3) << 3);
            unsigned i2 = 1u << ((y2 & 3) << 3);
            if ((y1 >> 2) == cb) incA += i1; else incB += i1;
            if ((y2 >> 2) == cb) incA += i2; else incB += i2;

            int x0 = min(max(cx - 1, 0), CV - 1);
            int x1 = min(max(cx,     0), CV - 1);
            int x2 = min(max(cx + 1, 0), CV - 1);
            int rows[3] = {x0, x1, x2};
            #pragma unroll
            for (int r = 0; r < 3; ++r) {
                int xi = rows[r];
                int base = xi << 5;
                atomicAdd(&cnt[base + ((cb + xi) & 31)], incA);
                if (incB) atomicAdd(&cnt[base + ((cb + 1 + xi) & 31)], incB);
            }
        }
        barrier_lds_only();   // atomics are LDS ops: lgkmcnt covers them

        // ---- epilogue: word w <-> output float4 w; re-zero in passing ----
        vfloat4* ob = (vfloat4*)(out + (size_t)(b0 + bb) * CV * CV);
        for (int w = tid; w < CV * CV / 4; w += 512) {
            int xi  = w >> 5;                     // row
            int idx = (xi << 5) + (((w & 31) + xi) & 31);
            unsigned v = cnt[idx];
            cnt[idx] = 0u;                        // free re-zero for next batch
            vfloat4 r;
            r.x = fminf(fmaxf(0.3f - 0.07f * (float)( v        & 255u), 0.0f), 1.0f);
            r.y = fminf(fmaxf(0.3f - 0.07f * (float)((v >>  8) & 255u), 0.0f), 1.0f);
            r.z = fminf(fmaxf(0.3f - 0.07f * (float)((v >> 16) & 255u), 0.0f), 1.0f);
            r.w = fminf(fmaxf(0.3f - 0.07f * (float)( v >> 24        ), 0.0f), 1.0f);
            __builtin_nontemporal_store(r, &ob[w]);
        }
        // lgkmcnt-only barrier: batch-0 stores keep draining under batch-1
        if (bb + 1 < NBPB) barrier_lds_only();
    }
}

extern "C" void kernel_launch(void* const* d_in, const int* in_sizes, int n_in,
                              void* d_out, int out_size, void* d_ws, size_t ws_size,
                              hipStream_t stream) {
    const float* x    = (const float*)d_in[0];   // [2048, 256]
    const float* W    = (const float*)d_in[1];   // [256, 192]
    const float* bias = (const float*)d_in[2];   // [192]
    float* out = (float*)d_out;

    fused_kernel<<<NB / NBPB, 512, 0, stream>>>(x, W, bias, out);
}

// Round 9
// 158.089 us; speedup vs baseline: 1.1750x; 1.0284x over previous
//
#include <hip/hip_runtime.h>
#include <math.h>

// Problem constants (from reference)
#define NB      2048        // batch
#define DIM     256         // input dim
#define SC6     192         // S*6 = 32 splines * 6 params
#define CV      128         // canvas size
#define NT      50          // samples along curve
#define NBPB    4           // batches per block (W amortization)
// W_STAMP = -0.07, BG = 0.3, SCALE = 1e-4

// log_prob per batch = 192*( -ln(1e-4) - 0.5*ln(2*pi) )  (raw == mu exactly)
// entropy  per batch = 192*( 0.5 + 0.5*ln(2*pi) + ln(1e-4) )
#define LPV  (1591.9491530441301f)
#define ENV  (-1495.9491530441301f)

// Output layout (flat, return order): sketch | log_prob | entropy | sample
#define SKETCH_N   ((size_t)NB * CV * CV)     // 33,554,432
#define LP_OFF     (SKETCH_N)
#define ENT_OFF    (LP_OFF + NB)
#define SAMPLE_OFF (ENT_OFF + NB)

typedef float vfloat4 __attribute__((ext_vector_type(4)));

// Workgroup barrier waiting ONLY on LDS ops (lgkmcnt), not global stores —
// __syncthreads() would emit s_waitcnt vmcnt(0) and drain the epilogue's
// stores on the critical path. All inter-phase deps here are LDS-only.
__device__ __forceinline__ void barrier_lds_only() {
    asm volatile("s_waitcnt lgkmcnt(0)\n\ts_barrier" ::: "memory");
}

// ---------------------------------------------------------------------------
// Fused kernel, one block (512 thr) per FOUR batches; grid 512 = 2 blocks/CU.
//  waves 0-2 (tid<192): thread j computes mu for 4 batches reading W[d][j]
//      once (W L2 traffic 200->100 MB; W-amortization is the proven win
//      axis); per-batch f64 chain strictly sequential d=0..255 ->
//      bit-identical mu; sigmoid f64; sample -> global; params*128 -> LDS.
//  waves 3-7, CONCURRENT: zero canvas, 50-entry f64 Bezier coeff table,
//      lp/ent constants.
//  per batch: paint u8-packed canvas (4 px/u32, 16 KB), ~4.5 LDS atomics
//      per point, per-row bank rotation; epilogue clip(0.3-0.07*cnt,0,1)
//      with PLAIN CACHED float4 stores (writes land in L2 at ~34 TB/s, HBM
//      writeback drains in background -> no store-issue backpressure, the
//      R8 nontemporal path serialized store phases at HBM rate) + re-zero.
// ---------------------------------------------------------------------------
__global__ __launch_bounds__(512) void fused_kernel(
    const float* __restrict__ x, const float* __restrict__ W,
    const float* __restrict__ bias, float* __restrict__ out)
{
    __shared__ unsigned int cnt[CV * CV / 4];     // 4096 words, u8-packed, 16 KB
    __shared__ double sp[NBPB][6][32];            // SoA params*128, 4 batches
    __shared__ double cfa[NT], cfb[NT], cfc[NT];  // (1-t)^2, 2(1-t)t, t^2

    const int b0  = blockIdx.x * NBPB;
    const int tid = threadIdx.x;

    if (tid < SC6) {
        // ---- gemm + sigmoid, 4 batches, W loaded once (f64 exact chains) ----
        const int j = tid;
        const float* xb = x + (size_t)b0 * DIM;   // wave-uniform -> s_load
        double a0 = 0.0, a1 = 0.0, a2 = 0.0, a3 = 0.0;
        #pragma unroll 8
        for (int d = 0; d < DIM; ++d) {
            double wd = (double)W[d * SC6 + j];
            a0 = fma((double)xb[d],           wd, a0);
            a1 = fma((double)xb[DIM + d],     wd, a1);
            a2 = fma((double)xb[2 * DIM + d], wd, a2);
            a3 = fma((double)xb[3 * DIM + d], wd, a3);
        }
        double bj = (double)bias[j];
        double s0 = 1.0 / (1.0 + exp(-(a0 + bj)));
        double s1 = 1.0 / (1.0 + exp(-(a1 + bj)));
        double s2 = 1.0 / (1.0 + exp(-(a2 + bj)));
        double s3 = 1.0 / (1.0 + exp(-(a3 + bj)));
        out[SAMPLE_OFF + (size_t)b0 * SC6 + j]       = (float)s0;
        out[SAMPLE_OFF + (size_t)(b0 + 1) * SC6 + j] = (float)s1;
        out[SAMPLE_OFF + (size_t)(b0 + 2) * SC6 + j] = (float)s2;
        out[SAMPLE_OFF + (size_t)(b0 + 3) * SC6 + j] = (float)s3;
        sp[0][j % 6][j / 6] = s0 * 128.0;         // CANVAS scale, SoA
        sp[1][j % 6][j / 6] = s1 * 128.0;
        sp[2][j % 6][j / 6] = s2 * 128.0;
        sp[3][j % 6][j / 6] = s3 * 128.0;
    } else {
        // ---- waves 3-7: canvas zero + coeff table + consts (concurrent) ----
        const int t2 = tid - SC6;                 // 0..319
        uint4* c4 = (uint4*)cnt;                  // 1024 uint4 words
        uint4 z = make_uint4(0u, 0u, 0u, 0u);
        for (int w = t2; w < 1024; w += 320) c4[w] = z;
        if (t2 < NT) {
            // np.linspace(0,1,50): t_k = k*fl64(1/49), endpoint forced to 1.0
            double t = (t2 == NT - 1) ? 1.0 : (double)t2 * (1.0 / 49.0);
            double u = 1.0 - t;
            cfa[t2] = u * u;                      // (1-t)**2
            cfb[t2] = (2.0 * u) * t;              // 2*(1-t)*t (ref assoc order)
            cfc[t2] = t * t;                      // t**2
        }
        if (t2 >= 56 && t2 < 60) out[LP_OFF  + b0 + (t2 - 56)] = LPV;
        if (t2 >= 60 && t2 < 64) out[ENT_OFF + b0 + (t2 - 60)] = ENV;
    }
    barrier_lds_only();

    #pragma unroll
    for (int bb = 0; bb < NBPB; ++bb) {
        // ---- paint: lane map s=i%32 scatters lanes across splines ----
        for (int i = tid; i < 32 * NT; i += 512) {
            int s = i & 31;
            int k = i >> 5;                       // 0..49
            double a  = cfa[k];
            double bq = cfb[k];
            double c  = cfc[k];
            double px = a * sp[bb][0][s] + bq * sp[bb][2][s] + c * sp[bb][4][s];
            double py = a * sp[bb][1][s] + bq * sp[bb][3][s] + c * sp[bb][5][s];
            int cx = (int)rint(px);               // round-half-even == np.round
            int cy = (int)rint(py);

            // clipped y-triple -> u8 increments for 1-2 adjacent 4-px words
            int y0 = min(max(cy - 1, 0), CV - 1);
            int y1 = min(max(cy,     0), CV - 1);
            int y2 = min(max(cy + 1, 0), CV - 1);
            int cb = y0 >> 2;                     // base word-column (0..31)
            unsigned incA = 1u << ((y0 & 3) << 3);
            unsigned incB = 0u;
            unsigned i1 = 1u << ((y1 & 3) << 3);
            unsigned i2 = 1u << ((y2 & 3) << 3);
            if ((y1 >> 2) == cb) incA += i1; else incB += i1;
            if ((y2 >> 2) == cb) incA += i2; else incB += i2;

            int x0 = min(max(cx - 1, 0), CV - 1);
            int x1 = min(max(cx,     0), CV - 1);
            int x2 = min(max(cx + 1, 0), CV - 1);
            int rows[3] = {x0, x1, x2};
            #pragma unroll
            for (int r = 0; r < 3; ++r) {
                int xi = rows[r];
                int base = xi << 5;
                atomicAdd(&cnt[base + ((cb + xi) & 31)], incA);
                if (incB) atomicAdd(&cnt[base + ((cb + 1 + xi) & 31)], incB);
            }
        }
        barrier_lds_only();   // LDS atomics covered by lgkmcnt

        // ---- epilogue: word w <-> output float4 w; re-zero in passing ----
        vfloat4* ob = (vfloat4*)(out + (size_t)(b0 + bb) * CV * CV);
        for (int w = tid; w < CV * CV / 4; w += 512) {
            int xi  = w >> 5;                     // row
            int idx = (xi << 5) + (((w & 31) + xi) & 31);
            unsigned v = cnt[idx];
            cnt[idx] = 0u;                        // free re-zero for next batch
            vfloat4 r;
            r.x = fminf(fmaxf(0.3f - 0.07f * (float)( v        & 255u), 0.0f), 1.0f);
            r.y = fminf(fmaxf(0.3f - 0.07f * (float)((v >>  8) & 255u), 0.0f), 1.0f);
            r.z = fminf(fmaxf(0.3f - 0.07f * (float)((v >> 16) & 255u), 0.0f), 1.0f);
            r.w = fminf(fmaxf(0.3f - 0.07f * (float)( v >> 24        ), 0.0f), 1.0f);
            ob[w] = r;                            // cached store -> L2
        }
        if (bb + 1 < NBPB) barrier_lds_only();
    }
}

extern "C" void kernel_launch(void* const* d_in, const int* in_sizes, int n_in,
                              void* d_out, int out_size, void* d_ws, size_t ws_size,
                              hipStream_t stream) {
    const float* x    = (const float*)d_in[0];   // [2048, 256]
    const float* W    = (const float*)d_in[1];   // [256, 192]
    const float* bias = (const float*)d_in[2];   // [192]
    float* out = (float*)d_out;

    fused_kernel<<<NB / NBPB, 512, 0, stream>>>(x, W, bias, out);
}